// Round 8
// baseline (263.313 us; speedup 1.0000x reference)
//
#include <hip/hip_runtime.h>

// CAM module: split x into bf16 hi/lo; energy = q qT (bf16x3, symmetric tiles,
// K-split x2: half-0 -> e0 (ws), half-1 -> e1 (in d_out scratch)); transpose xh -> xt
// (reusing xl buffer); softmin(e0+e1) -> bf16 attn; out = gamma*(attn q) + x.
// B=16, C=512, N=64*64=4096

#define BATCH 16
#define CCH   512
#define NSP   4096

typedef __attribute__((ext_vector_type(8))) short bfx8;
typedef __attribute__((ext_vector_type(4))) short bfx4;
typedef __attribute__((ext_vector_type(4))) float fx4;
typedef __attribute__((ext_vector_type(2))) float fx2;

__device__ __forceinline__ short f2bf(float v) {
    union { float f; unsigned u; } a; a.f = v;
    unsigned r = a.u + 0x7fffu + ((a.u >> 16) & 1u);   // RNE
    return (short)(r >> 16);
}
__device__ __forceinline__ float bf2f(short s) {
    union { unsigned u; float f; } a; a.u = ((unsigned)(unsigned short)s) << 16;
    return a.f;
}

// async global(16B/lane) -> LDS (wave-uniform base + lane*16)
__device__ __forceinline__ void gload16(const short* g, short* l) {
    __builtin_amdgcn_global_load_lds((const __attribute__((address_space(1))) void*)g,
                                     (__attribute__((address_space(3))) void*)l, 16, 0, 0);
}

// ---------------- Kernel 0: split x -> xh (RNE bf16) + xl (residual bf16) ----------------
__global__ __launch_bounds__(256) void split_kernel(const float* __restrict__ x,
                                                    short* __restrict__ xh,
                                                    short* __restrict__ xl) {
    size_t stride = (size_t)gridDim.x * 256;
    size_t total8 = (size_t)BATCH * CCH * NSP / 8;
    for (size_t u = (size_t)blockIdx.x * 256 + threadIdx.x; u < total8; u += stride) {
        size_t i = u * 8;
        fx4 a = *(const fx4*)(x + i);
        fx4 b = *(const fx4*)(x + i + 4);
        bfx8 h, l;
#pragma unroll
        for (int e = 0; e < 4; ++e) {
            short ha = f2bf(a[e]); h[e]     = ha; l[e]     = f2bf(a[e] - bf2f(ha));
            short hb = f2bf(b[e]); h[e + 4] = hb; l[e + 4] = f2bf(b[e] - bf2f(hb));
        }
        *(bfx8*)(xh + i) = h;
        *(bfx8*)(xl + i) = l;
    }
}

// ---------------- Kernel 1: energy = q qT, bf16x3, symmetric tiles, K-split x2 ----------------
// 64x64 tile, 4 waves (32x32 each), BK=32, LDS 32 KiB dbuf, K=2048 per block.
// khalf 0 -> e0, khalf 1 -> e1 (summed in softmax). Deterministic: disjoint stores.
__global__ __launch_bounds__(256) void energy_kernel(const short* __restrict__ xh,
                                                     const short* __restrict__ xl,
                                                     float* __restrict__ e0,
                                                     float* __restrict__ e1) {
    // XCD-chunked bijective swizzle: 1152 blocks = 8 xcds x 144
    int orig = blockIdx.x;
    int wgid = (orig & 7) * 144 + (orig >> 3);
    int khalf = wgid >= 576;
    int rest  = wgid - khalf * 576;
    int b = rest / 36;
    int t = rest % 36;
    int ti = 0, rem = t;
    while (rem >= 8 - ti) { rem -= 8 - ti; ++ti; }
    int tj = ti + rem;
    int c0 = ti * 64, d0 = tj * 64;
    bool diag = (ti == tj);
    const short* qh = xh + (size_t)b * CCH * NSP;
    const short* ql = xl + (size_t)b * CCH * NSP;
    float* eout = khalf ? e1 : e0;
    size_t kbase = (size_t)khalf * 2048;

    __shared__ short S[2][4][64][32];   // [buf][Ah,Al,Bh,Bl][row][k]  = 32 KiB

    int tid  = threadIdx.x;
    int lane = tid & 63;
    int w    = tid >> 6;
    int wr   = (w >> 1) * 32;
    int wc   = (w & 1) * 32;

    int rb   = w * 16;
    int srow = lane >> 2;                       // 0..15
    int gch  = (lane & 3) ^ ((lane >> 3) & 3);  // pre-swizzled source chunk

    auto STAGE = [&](int buf, int kt) {
        size_t koff = kbase + (size_t)kt * 32 + gch * 8;
        gload16(qh + (size_t)(c0 + rb + srow) * NSP + koff, &S[buf][0][rb][0]);
        gload16(ql + (size_t)(c0 + rb + srow) * NSP + koff, &S[buf][1][rb][0]);
        if (!diag) {
            gload16(qh + (size_t)(d0 + rb + srow) * NSP + koff, &S[buf][2][rb][0]);
            gload16(ql + (size_t)(d0 + rb + srow) * NSP + koff, &S[buf][3][rb][0]);
        }
    };

    fx4 acc[2][2];
#pragma unroll
    for (int i = 0; i < 2; i++)
#pragma unroll
        for (int j = 0; j < 2; j++) acc[i][j] = (fx4)(0.0f);

    STAGE(0, 0);
    __syncthreads();

    const char* Sb = (const char*)&S[0][0][0][0];
    const int bmH = diag ? 0 : 2, bmL = diag ? 1 : 3;
    int h = lane >> 4;
    int cur = 0;
    const int NT = 2048 / 32;           // 64
    for (int kt = 0; kt < NT; ++kt) {
        bfx8 ah_[2], al_[2], bh_[2], bl_[2];
        const char* Sc = Sb + cur * (4 * 64 * 64);
#pragma unroll
        for (int mi = 0; mi < 2; ++mi) {
            int r  = wr + mi * 16 + (lane & 15);
            int bo = r * 64 + ((h ^ ((r >> 1) & 3)) << 4);
            ah_[mi] = *(const bfx8*)(Sc + 0 * 4096 + bo);
            al_[mi] = *(const bfx8*)(Sc + 1 * 4096 + bo);
        }
#pragma unroll
        for (int ni = 0; ni < 2; ++ni) {
            int r  = wc + ni * 16 + (lane & 15);
            int bo = r * 64 + ((h ^ ((r >> 1) & 3)) << 4);
            bh_[ni] = *(const bfx8*)(Sc + bmH * 4096 + bo);
            bl_[ni] = *(const bfx8*)(Sc + bmL * 4096 + bo);
        }
        if (kt + 1 < NT) STAGE(cur ^ 1, kt + 1);
#pragma unroll
        for (int mi = 0; mi < 2; ++mi)
#pragma unroll
            for (int ni = 0; ni < 2; ++ni) {
                acc[mi][ni] = __builtin_amdgcn_mfma_f32_16x16x32_bf16(ah_[mi], bh_[ni], acc[mi][ni], 0, 0, 0);
                acc[mi][ni] = __builtin_amdgcn_mfma_f32_16x16x32_bf16(ah_[mi], bl_[ni], acc[mi][ni], 0, 0, 0);
                acc[mi][ni] = __builtin_amdgcn_mfma_f32_16x16x32_bf16(al_[mi], bh_[ni], acc[mi][ni], 0, 0, 0);
            }
        __syncthreads();
        cur ^= 1;
    }

    int colw = lane & 15;
    int rowg = (lane >> 4) * 4;
#pragma unroll
    for (int mi = 0; mi < 2; ++mi)
#pragma unroll
        for (int ni = 0; ni < 2; ++ni) {
            int cb = c0 + wr + mi * 16 + rowg;
            int d  = d0 + wc + ni * 16 + colw;
#pragma unroll
            for (int r = 0; r < 4; ++r) {
                int c = cb + r;
                float v = acc[mi][ni][r];
                eout[((size_t)b * CCH + c) * CCH + d] = v;
                if (!diag)
                    eout[((size_t)b * CCH + d) * CCH + c] = v;
            }
        }
}

// ---------------- Kernel 1.5: transpose xh[b][c][n] -> xt[b][n][c] (bf16) ----------------
__global__ __launch_bounds__(256) void transpose_kernel(const short* __restrict__ xh,
                                                        short* __restrict__ xt) {
    int blk = blockIdx.x;              // 16 * 8 * 64 = 8192
    int b  = blk >> 9;
    int t  = blk & 511;
    int ct = t >> 6;                   // c-tile 0..7
    int nt = t & 63;                   // n-tile 0..63
    int c0 = ct * 64, n0 = nt * 64;
    const short* src = xh + (size_t)b * CCH * NSP;
    short*       dst = xt + (size_t)b * NSP * CCH;

    __shared__ short Lt[64][64];       // [n][c], 128B rows, swizzled 16B chunks

    int tid = threadIdx.x;
    int p  = tid & 31;                 // col-pair: n = 2p, 2p+1
    int dr = tid >> 5;                 // c-chunk 0..7

    unsigned wv[8];
    const short* sp = src + (size_t)(c0 + dr * 8) * NSP + n0 + 2 * p;
#pragma unroll
    for (int i = 0; i < 8; ++i) wv[i] = *(const unsigned*)(sp + (size_t)i * NSP);
    bfx8 q0, q1;
#pragma unroll
    for (int i = 0; i < 8; ++i) { q0[i] = (short)(wv[i] & 0xffff); q1[i] = (short)(wv[i] >> 16); }
    int slot = dr ^ (p & 7);
    *(bfx8*)(&Lt[0][0] + (2 * p) * 64 + slot * 8)     = q0;
    *(bfx8*)(&Lt[0][0] + (2 * p + 1) * 64 + slot * 8) = q1;
    __syncthreads();

#pragma unroll
    for (int it = 0; it < 2; ++it) {
        int n  = it * 32 + (tid >> 3);
        int ch = tid & 7;
        bfx8 v = *(const bfx8*)(&Lt[0][0] + n * 64 + (ch ^ ((n >> 1) & 7)) * 8);
        *(bfx8*)(dst + (size_t)(n0 + n) * CCH + c0 + ch * 8) = v;
    }
}

// ---------------- Kernel 2: softmin over rows of e0+e1; writes bf16 attn into e0 ----------------
__global__ __launch_bounds__(256) void softmax_kernel(float* __restrict__ e0,
                                                      const float* __restrict__ e1) {
    size_t row = blockIdx.x;
    float* ep = e0 + row * CCH;
    const float* eq = e1 + row * CCH;
    int tid = threadIdx.x;
    fx2 va = *(const fx2*)(ep + 2 * tid);
    fx2 vb = *(const fx2*)(eq + 2 * tid);
    float v0 = va[0] + vb[0];
    float v1 = va[1] + vb[1];

    float m = fminf(v0, v1);
#pragma unroll
    for (int off = 32; off; off >>= 1) m = fminf(m, __shfl_xor(m, off));
    __shared__ float redm[4];
    __shared__ float reds[4];
    if ((tid & 63) == 0) redm[tid >> 6] = m;
    __syncthreads();
    m = fminf(fminf(redm[0], redm[1]), fminf(redm[2], redm[3]));

    float w0 = __expf(m - v0);
    float w1 = __expf(m - v1);
    float s = w0 + w1;
#pragma unroll
    for (int off = 32; off; off >>= 1) s += __shfl_xor(s, off);
    if ((tid & 63) == 0) reds[tid >> 6] = s;
    __syncthreads();
    s = (reds[0] + reds[1]) + (reds[2] + reds[3]);
    float inv = 1.0f / s;
    unsigned uw = ((unsigned)(unsigned short)f2bf(w0 * inv)) |
                  (((unsigned)(unsigned short)f2bf(w1 * inv)) << 16);
    ((unsigned*)ep)[tid] = uw;   // safe: all reads completed before barriers
}

// ---------------- Kernel 3: out = gamma * (attn @ q) + x ----------------
// 128x128 tile, BK=32, 4 waves each owning 64x64. A (attn rows) and B (xt rows)
// staged via global_load_lds with pre-swizzled source; LDS dbuf 32 KiB.
__global__ __launch_bounds__(256, 3) void out_kernel(const float* __restrict__ x,
                                                     const short* __restrict__ attnb, // 1024-short rows
                                                     const short* __restrict__ xt,    // [n][c] bf16
                                                     const float* __restrict__ gamma,
                                                     float* __restrict__ out) {
    // XCD-chunked swizzle: 2048 blocks = 8 x 256
    int orig = blockIdx.x;
    int blk  = (orig & 7) * 256 + (orig >> 3);
    int b   = blk >> 7;
    int t   = blk & 127;
    int c0  = (t >> 5) * 128;
    int n0  = (t & 31) * 128;
    const float* xb = x + (size_t)b * CCH * NSP;
    const short* ab = attnb + (size_t)b * CCH * 1024;
    const short* qt = xt + (size_t)b * NSP * CCH;

    __shared__ short SA[2][128][32];
    __shared__ short SB[2][128][32];

    int tid  = threadIdx.x;
    int lane = tid & 63;
    int w    = tid >> 6;
    int wr   = (w >> 1) * 64;
    int wc   = (w & 1) * 64;

    int srow = lane >> 2;
    int gch  = (lane & 3) ^ ((lane >> 3) & 3);

    auto STAGE = [&](int buf, int kt) {
#pragma unroll
        for (int hf = 0; hf < 2; ++hf) {
            int rg = hf * 64 + w * 16;
            gload16(ab + (size_t)(c0 + rg + srow) * 1024 + kt * 32 + gch * 8, &SA[buf][rg][0]);
            gload16(qt + (size_t)(n0 + rg + srow) * 512  + kt * 32 + gch * 8, &SB[buf][rg][0]);
        }
    };

    fx4 acc[4][4];
#pragma unroll
    for (int i = 0; i < 4; i++)
#pragma unroll
        for (int j = 0; j < 4; j++) acc[i][j] = (fx4)(0.0f);

    STAGE(0, 0);
    __syncthreads();

    int h = lane >> 4;
    int cur = 0;
    const int NT = CCH / 32;            // 16
    for (int kt = 0; kt < NT; ++kt) {
        bfx8 af[4], bf[4];
#pragma unroll
        for (int mi = 0; mi < 4; ++mi) {
            int r  = wr + mi * 16 + (lane & 15);
            af[mi] = *(const bfx8*)((const char*)&SA[cur][0][0] + r * 64 + ((h ^ ((r >> 1) & 3)) << 4));
        }
#pragma unroll
        for (int ni = 0; ni < 4; ++ni) {
            int r  = wc + ni * 16 + (lane & 15);
            bf[ni] = *(const bfx8*)((const char*)&SB[cur][0][0] + r * 64 + ((h ^ ((r >> 1) & 3)) << 4));
        }
        if (kt + 1 < NT) STAGE(cur ^ 1, kt + 1);
#pragma unroll
        for (int mi = 0; mi < 4; ++mi)
#pragma unroll
            for (int ni = 0; ni < 4; ++ni)
                acc[mi][ni] = __builtin_amdgcn_mfma_f32_16x16x32_bf16(af[mi], bf[ni], acc[mi][ni], 0, 0, 0);
        __syncthreads();
        cur ^= 1;
    }

    float g = gamma[0];
    int colw = lane & 15;
    int rowg = (lane >> 4) * 4;
#pragma unroll
    for (int mi = 0; mi < 4; ++mi)
#pragma unroll
        for (int ni = 0; ni < 4; ++ni) {
            int n = n0 + wc + ni * 16 + colw;
#pragma unroll
            for (int r = 0; r < 4; ++r) {
                int c = c0 + wr + mi * 16 + rowg + r;
                size_t off = ((size_t)b * CCH + c) * NSP + n;
                out[off] = g * acc[mi][ni][r] + xb[(size_t)c * NSP + n];
            }
        }
}

extern "C" void kernel_launch(void* const* d_in, const int* in_sizes, int n_in,
                              void* d_out, int out_size, void* d_ws, size_t ws_size,
                              hipStream_t stream) {
    (void)in_sizes; (void)n_in; (void)out_size; (void)ws_size;
    const float* x     = (const float*)d_in[0];
    const float* gamma = (const float*)d_in[1];
    float*       out   = (float*)d_out;

    size_t nel  = (size_t)BATCH * CCH * NSP;
    size_t bfsz = nel * sizeof(short);                   // 64 MiB
    short* xhp    = (short*)d_ws;
    short* xlp    = (short*)((char*)d_ws + bfsz);        // xl; reused as xt after energy
    float* e0     = (float*)((char*)d_ws + 2 * bfsz);    // 16 MiB
    float* e1     = out;                                 // scratch in d_out (dead until out_kernel)

    split_kernel     <<<2048, 256, 0, stream>>>(x, xhp, xlp);
    energy_kernel    <<<BATCH * 36 * 2, 256, 0, stream>>>(xhp, xlp, e0, e1);
    transpose_kernel <<<BATCH * 512, 256, 0, stream>>>(xhp, xlp);       // xl -> xt
    softmax_kernel   <<<BATCH * CCH, 256, 0, stream>>>(e0, e1);
    out_kernel       <<<BATCH * 128, 256, 0, stream>>>(x, (const short*)e0, xlp, gamma, out);
}

// Round 9
// 263.308 us; speedup vs baseline: 1.0000x; 1.0000x over previous
//
#include <hip/hip_runtime.h>

// CAM module: fused split+transpose (x -> xh, xl, xt); energy = q qT (bf16x3,
// symmetric tiles, BK=32 dbuf global_load_lds); softmin -> bf16 attn;
// out = gamma*(attn q) + x (128x128 gload_lds GEMM).
// B=16, C=512, N=64*64=4096

#define BATCH 16
#define CCH   512
#define NSP   4096

typedef __attribute__((ext_vector_type(8))) short bfx8;
typedef __attribute__((ext_vector_type(4))) short bfx4;
typedef __attribute__((ext_vector_type(4))) float fx4;
typedef __attribute__((ext_vector_type(2))) float fx2;

__device__ __forceinline__ short f2bf(float v) {
    union { float f; unsigned u; } a; a.f = v;
    unsigned r = a.u + 0x7fffu + ((a.u >> 16) & 1u);   // RNE
    return (short)(r >> 16);
}
__device__ __forceinline__ float bf2f(short s) {
    union { unsigned u; float f; } a; a.u = ((unsigned)(unsigned short)s) << 16;
    return a.f;
}

// async global(16B/lane) -> LDS (wave-uniform base + lane*16)
__device__ __forceinline__ void gload16(const short* g, short* l) {
    __builtin_amdgcn_global_load_lds((const __attribute__((address_space(1))) void*)g,
                                     (__attribute__((address_space(3))) void*)l, 16, 0, 0);
}

// ---------------- Kernel 0a (fused path): x -> xh, xl, and xt[b][n][c] ----------------
// 64c x 64n tile. Phase1: row-coalesced reads/writes + h into LDS A (c-major, swizzled).
// Phase2: u32 column gather (A) -> n-major LDS B (swizzled) -> coalesced xt rows.
// All LDS phases verified uniform-bank (optimal) or 2-way (free).
__global__ __launch_bounds__(256) void fused_split_kernel(const float* __restrict__ x,
                                                          short* __restrict__ xh,
                                                          short* __restrict__ xl,
                                                          short* __restrict__ xt) {
    int blk = blockIdx.x;              // 16*8*64 = 8192
    int b  = blk >> 9;
    int t  = blk & 511;
    int ct = t >> 6;                   // c-tile 0..7
    int nt = t & 63;                   // n-tile 0..63
    int c0 = ct * 64, n0 = nt * 64;
    const float* xb  = x  + (size_t)b * CCH * NSP;
    short*       xhb = xh + (size_t)b * CCH * NSP;
    short*       xlb = xl + (size_t)b * CCH * NSP;
    short*       xtb = xt + (size_t)b * NSP * CCH;

    __shared__ short A[64][64];        // [c][n], chunk ch at slot ch^(c&7)
    __shared__ short Bn[64][64];       // [n][c], chunk dr at slot dr^((n>>1)&7)

    int tid = threadIdx.x;

    // phase 1: read x rows, write xh/xl (coalesced), stash h in A
#pragma unroll
    for (int s = 0; s < 2; ++s) {
        int idx = s * 256 + tid;
        int row = idx >> 3;            // c-row 0..63
        int ch  = idx & 7;             // n-chunk
        const float* p = xb + (size_t)(c0 + row) * NSP + n0 + ch * 8;
        fx4 a = *(const fx4*)p;
        fx4 q = *(const fx4*)(p + 4);
        bfx8 h, l;
#pragma unroll
        for (int e = 0; e < 4; ++e) {
            short ha = f2bf(a[e]); h[e]     = ha; l[e]     = f2bf(a[e] - bf2f(ha));
            short hb = f2bf(q[e]); h[e + 4] = hb; l[e + 4] = f2bf(q[e] - bf2f(hb));
        }
        size_t go = (size_t)(c0 + row) * NSP + n0 + ch * 8;
        *(bfx8*)(xhb + go) = h;
        *(bfx8*)(xlb + go) = l;
        *(bfx8*)(&A[row][(ch ^ (row & 7)) * 8]) = h;
    }
    __syncthreads();

    // phase 2a: u32 column gather (n-pair 2p,2p+1 across 8 c-rows)
    int p  = tid & 31;
    int dr = tid >> 5;                 // c-oct 0..7
    unsigned wv[8];
#pragma unroll
    for (int i = 0; i < 8; ++i) {
        int r = dr * 8 + i;
        int byte = r * 128 + ((((p >> 2) ^ (r & 7)) * 8 + (2 * p & 7)) * 2);
        wv[i] = *(const unsigned*)((const char*)&A[0][0] + byte);
    }
    bfx8 q0, q1;
#pragma unroll
    for (int i = 0; i < 8; ++i) { q0[i] = (short)(wv[i] & 0xffff); q1[i] = (short)(wv[i] >> 16); }

    // phase 2b: write n-major tile (separate LDS array, no barrier needed before)
    int slot2 = dr ^ (p & 7);
    *(bfx8*)(&Bn[2 * p][slot2 * 8])     = q0;
    *(bfx8*)(&Bn[2 * p + 1][slot2 * 8]) = q1;
    __syncthreads();

    // phase 2c: coalesced xt row writes
#pragma unroll
    for (int it = 0; it < 2; ++it) {
        int n  = it * 32 + (tid >> 3);
        int ch = tid & 7;
        bfx8 v = *(const bfx8*)(&Bn[n][(ch ^ ((n >> 1) & 7)) * 8]);
        *(bfx8*)(xtb + (size_t)(n0 + n) * CCH + c0 + ch * 8) = v;
    }
}

// ---------------- Kernel 0b (fallback): split x -> xh + xl ----------------
__global__ __launch_bounds__(256) void split_kernel(const float* __restrict__ x,
                                                    short* __restrict__ xh,
                                                    short* __restrict__ xl) {
    size_t stride = (size_t)gridDim.x * 256;
    size_t total8 = (size_t)BATCH * CCH * NSP / 8;
    for (size_t u = (size_t)blockIdx.x * 256 + threadIdx.x; u < total8; u += stride) {
        size_t i = u * 8;
        fx4 a = *(const fx4*)(x + i);
        fx4 b = *(const fx4*)(x + i + 4);
        bfx8 h, l;
#pragma unroll
        for (int e = 0; e < 4; ++e) {
            short ha = f2bf(a[e]); h[e]     = ha; l[e]     = f2bf(a[e] - bf2f(ha));
            short hb = f2bf(b[e]); h[e + 4] = hb; l[e + 4] = f2bf(b[e] - bf2f(hb));
        }
        *(bfx8*)(xh + i) = h;
        *(bfx8*)(xl + i) = l;
    }
}

// ---------------- Kernel 1: energy = q qT, bf16x3, symmetric tiles (R7, proven) ----------------
// 64x64 tile, 4 waves (32x32 each), BK=32, LDS 32 KiB dbuf, full K per block.
__global__ __launch_bounds__(256) void energy_kernel(const short* __restrict__ xh,
                                                     const short* __restrict__ xl,
                                                     float* __restrict__ energy) {
    int orig = blockIdx.x;
    int wgid = (orig & 7) * 72 + (orig >> 3);   // 576 = 8 xcds x 72
    int b = wgid / 36;
    int t = wgid % 36;
    int ti = 0, rem = t;
    while (rem >= 8 - ti) { rem -= 8 - ti; ++ti; }
    int tj = ti + rem;
    int c0 = ti * 64, d0 = tj * 64;
    bool diag = (ti == tj);
    const short* qh = xh + (size_t)b * CCH * NSP;
    const short* ql = xl + (size_t)b * CCH * NSP;

    __shared__ short S[2][4][64][32];   // [buf][Ah,Al,Bh,Bl][row][k]  = 32 KiB

    int tid  = threadIdx.x;
    int lane = tid & 63;
    int w    = tid >> 6;
    int wr   = (w >> 1) * 32;
    int wc   = (w & 1) * 32;

    int rb   = w * 16;
    int srow = lane >> 2;                       // 0..15
    int gch  = (lane & 3) ^ ((lane >> 3) & 3);  // pre-swizzled source chunk

    auto STAGE = [&](int buf, int kt) {
        size_t koff = (size_t)kt * 32 + gch * 8;
        gload16(qh + (size_t)(c0 + rb + srow) * NSP + koff, &S[buf][0][rb][0]);
        gload16(ql + (size_t)(c0 + rb + srow) * NSP + koff, &S[buf][1][rb][0]);
        if (!diag) {
            gload16(qh + (size_t)(d0 + rb + srow) * NSP + koff, &S[buf][2][rb][0]);
            gload16(ql + (size_t)(d0 + rb + srow) * NSP + koff, &S[buf][3][rb][0]);
        }
    };

    fx4 acc[2][2];
#pragma unroll
    for (int i = 0; i < 2; i++)
#pragma unroll
        for (int j = 0; j < 2; j++) acc[i][j] = (fx4)(0.0f);

    STAGE(0, 0);
    __syncthreads();

    const char* Sb = (const char*)&S[0][0][0][0];
    const int bmH = diag ? 0 : 2, bmL = diag ? 1 : 3;
    int h = lane >> 4;
    int cur = 0;
    const int NT = NSP / 32;
    for (int kt = 0; kt < NT; ++kt) {
        bfx8 ah_[2], al_[2], bh_[2], bl_[2];
        const char* Sc = Sb + cur * (4 * 64 * 64);
#pragma unroll
        for (int mi = 0; mi < 2; ++mi) {
            int r  = wr + mi * 16 + (lane & 15);
            int bo = r * 64 + ((h ^ ((r >> 1) & 3)) << 4);
            ah_[mi] = *(const bfx8*)(Sc + 0 * 4096 + bo);
            al_[mi] = *(const bfx8*)(Sc + 1 * 4096 + bo);
        }
#pragma unroll
        for (int ni = 0; ni < 2; ++ni) {
            int r  = wc + ni * 16 + (lane & 15);
            int bo = r * 64 + ((h ^ ((r >> 1) & 3)) << 4);
            bh_[ni] = *(const bfx8*)(Sc + bmH * 4096 + bo);
            bl_[ni] = *(const bfx8*)(Sc + bmL * 4096 + bo);
        }
        if (kt + 1 < NT) STAGE(cur ^ 1, kt + 1);
#pragma unroll
        for (int mi = 0; mi < 2; ++mi)
#pragma unroll
            for (int ni = 0; ni < 2; ++ni) {
                acc[mi][ni] = __builtin_amdgcn_mfma_f32_16x16x32_bf16(ah_[mi], bh_[ni], acc[mi][ni], 0, 0, 0);
                acc[mi][ni] = __builtin_amdgcn_mfma_f32_16x16x32_bf16(ah_[mi], bl_[ni], acc[mi][ni], 0, 0, 0);
                acc[mi][ni] = __builtin_amdgcn_mfma_f32_16x16x32_bf16(al_[mi], bh_[ni], acc[mi][ni], 0, 0, 0);
            }
        __syncthreads();
        cur ^= 1;
    }

    int colw = lane & 15;
    int rowg = (lane >> 4) * 4;
#pragma unroll
    for (int mi = 0; mi < 2; ++mi)
#pragma unroll
        for (int ni = 0; ni < 2; ++ni) {
            int cb = c0 + wr + mi * 16 + rowg;
            int d  = d0 + wc + ni * 16 + colw;
#pragma unroll
            for (int r = 0; r < 4; ++r) {
                int c = cb + r;
                float v = acc[mi][ni][r];
                energy[((size_t)b * CCH + c) * CCH + d] = v;
                if (!diag)
                    energy[((size_t)b * CCH + d) * CCH + c] = v;
            }
        }
}

// ---------------- Kernel 1.5 (fallback): transpose xh[b][c][n] -> xt[b][n][c] ----------------
__global__ __launch_bounds__(256) void transpose_kernel(const short* __restrict__ xh,
                                                        short* __restrict__ xt) {
    int blk = blockIdx.x;              // 8192
    int b  = blk >> 9;
    int t  = blk & 511;
    int ct = t >> 6;
    int nt = t & 63;
    int c0 = ct * 64, n0 = nt * 64;
    const short* src = xh + (size_t)b * CCH * NSP;
    short*       dst = xt + (size_t)b * NSP * CCH;

    __shared__ short Lt[64][64];

    int tid = threadIdx.x;
    int p  = tid & 31;
    int dr = tid >> 5;

    unsigned wv[8];
    const short* sp = src + (size_t)(c0 + dr * 8) * NSP + n0 + 2 * p;
#pragma unroll
    for (int i = 0; i < 8; ++i) wv[i] = *(const unsigned*)(sp + (size_t)i * NSP);
    bfx8 q0, q1;
#pragma unroll
    for (int i = 0; i < 8; ++i) { q0[i] = (short)(wv[i] & 0xffff); q1[i] = (short)(wv[i] >> 16); }
    int slot = dr ^ (p & 7);
    *(bfx8*)(&Lt[0][0] + (2 * p) * 64 + slot * 8)     = q0;
    *(bfx8*)(&Lt[0][0] + (2 * p + 1) * 64 + slot * 8) = q1;
    __syncthreads();

#pragma unroll
    for (int it = 0; it < 2; ++it) {
        int n  = it * 32 + (tid >> 3);
        int ch = tid & 7;
        bfx8 v = *(const bfx8*)(&Lt[0][0] + n * 64 + (ch ^ ((n >> 1) & 7)) * 8);
        *(bfx8*)(dst + (size_t)(n0 + n) * CCH + c0 + ch * 8) = v;
    }
}

// ---------------- Kernel 2: softmin over rows; writes bf16 attn in-place ----------------
__global__ __launch_bounds__(256) void softmax_kernel(float* __restrict__ energy) {
    size_t row = blockIdx.x;
    float* e = energy + row * CCH;
    int tid = threadIdx.x;
    fx2 v = *(const fx2*)(e + 2 * tid);

    float m = fminf(v[0], v[1]);
#pragma unroll
    for (int off = 32; off; off >>= 1) m = fminf(m, __shfl_xor(m, off));
    __shared__ float redm[4];
    __shared__ float reds[4];
    if ((tid & 63) == 0) redm[tid >> 6] = m;
    __syncthreads();
    m = fminf(fminf(redm[0], redm[1]), fminf(redm[2], redm[3]));

    float w0 = __expf(m - v[0]);
    float w1 = __expf(m - v[1]);
    float s = w0 + w1;
#pragma unroll
    for (int off = 32; off; off >>= 1) s += __shfl_xor(s, off);
    if ((tid & 63) == 0) reds[tid >> 6] = s;
    __syncthreads();
    s = (reds[0] + reds[1]) + (reds[2] + reds[3]);
    float inv = 1.0f / s;
    unsigned uw = ((unsigned)(unsigned short)f2bf(w0 * inv)) |
                  (((unsigned)(unsigned short)f2bf(w1 * inv)) << 16);
    ((unsigned*)e)[tid] = uw;   // safe: all reads completed before barriers
}

// ---------------- Kernel 3: out = gamma * (attn @ q) + x ----------------
// 128x128 tile, BK=32, 4 waves each owning 64x64. A (attn rows) and B (xt rows)
// staged via global_load_lds with pre-swizzled source; LDS dbuf 32 KiB.
__global__ __launch_bounds__(256, 3) void out_kernel(const float* __restrict__ x,
                                                     const short* __restrict__ attnb, // 1024-short rows
                                                     const short* __restrict__ xt,    // [n][c] bf16
                                                     const float* __restrict__ gamma,
                                                     float* __restrict__ out) {
    int orig = blockIdx.x;
    int blk  = (orig & 7) * 256 + (orig >> 3);   // 2048 = 8 x 256
    int b   = blk >> 7;
    int t   = blk & 127;
    int c0  = (t >> 5) * 128;
    int n0  = (t & 31) * 128;
    const float* xb = x + (size_t)b * CCH * NSP;
    const short* ab = attnb + (size_t)b * CCH * 1024;
    const short* qt = xt + (size_t)b * NSP * CCH;

    __shared__ short SA[2][128][32];
    __shared__ short SB[2][128][32];

    int tid  = threadIdx.x;
    int lane = tid & 63;
    int w    = tid >> 6;
    int wr   = (w >> 1) * 64;
    int wc   = (w & 1) * 64;

    int srow = lane >> 2;
    int gch  = (lane & 3) ^ ((lane >> 3) & 3);

    auto STAGE = [&](int buf, int kt) {
#pragma unroll
        for (int hf = 0; hf < 2; ++hf) {
            int rg = hf * 64 + w * 16;
            gload16(ab + (size_t)(c0 + rg + srow) * 1024 + kt * 32 + gch * 8, &SA[buf][rg][0]);
            gload16(qt + (size_t)(n0 + rg + srow) * 512  + kt * 32 + gch * 8, &SB[buf][rg][0]);
        }
    };

    fx4 acc[4][4];
#pragma unroll
    for (int i = 0; i < 4; i++)
#pragma unroll
        for (int j = 0; j < 4; j++) acc[i][j] = (fx4)(0.0f);

    STAGE(0, 0);
    __syncthreads();

    int h = lane >> 4;
    int cur = 0;
    const int NT = CCH / 32;            // 16
    for (int kt = 0; kt < NT; ++kt) {
        bfx8 af[4], bf[4];
#pragma unroll
        for (int mi = 0; mi < 4; ++mi) {
            int r  = wr + mi * 16 + (lane & 15);
            af[mi] = *(const bfx8*)((const char*)&SA[cur][0][0] + r * 64 + ((h ^ ((r >> 1) & 3)) << 4));
        }
#pragma unroll
        for (int ni = 0; ni < 4; ++ni) {
            int r  = wc + ni * 16 + (lane & 15);
            bf[ni] = *(const bfx8*)((const char*)&SB[cur][0][0] + r * 64 + ((h ^ ((r >> 1) & 3)) << 4));
        }
        if (kt + 1 < NT) STAGE(cur ^ 1, kt + 1);
#pragma unroll
        for (int mi = 0; mi < 4; ++mi)
#pragma unroll
            for (int ni = 0; ni < 4; ++ni)
                acc[mi][ni] = __builtin_amdgcn_mfma_f32_16x16x32_bf16(af[mi], bf[ni], acc[mi][ni], 0, 0, 0);
        __syncthreads();
        cur ^= 1;
    }

    float g = gamma[0];
    int colw = lane & 15;
    int rowg = (lane >> 4) * 4;
#pragma unroll
    for (int mi = 0; mi < 4; ++mi)
#pragma unroll
        for (int ni = 0; ni < 4; ++ni) {
            int n = n0 + wc + ni * 16 + colw;
#pragma unroll
            for (int r = 0; r < 4; ++r) {
                int c = c0 + wr + mi * 16 + rowg + r;
                size_t off = ((size_t)b * CCH + c) * NSP + n;
                out[off] = g * acc[mi][ni][r] + xb[(size_t)c * NSP + n];
            }
        }
}

extern "C" void kernel_launch(void* const* d_in, const int* in_sizes, int n_in,
                              void* d_out, int out_size, void* d_ws, size_t ws_size,
                              hipStream_t stream) {
    (void)in_sizes; (void)n_in; (void)out_size;
    const float* x     = (const float*)d_in[0];
    const float* gamma = (const float*)d_in[1];
    float*       out   = (float*)d_out;

    size_t nel  = (size_t)BATCH * CCH * NSP;
    size_t bfsz = nel * sizeof(short);                   // ~67 MB
    size_t esz  = (size_t)BATCH * CCH * CCH * 4;         // ~17 MB

    if (ws_size >= 3 * bfsz + esz) {
        // fused path: xh | xl | xt | e0
        short* xhp = (short*)d_ws;
        short* xlp = (short*)((char*)d_ws + bfsz);
        short* xtp = (short*)((char*)d_ws + 2 * bfsz);
        float* e0  = (float*)((char*)d_ws + 3 * bfsz);
        fused_split_kernel<<<BATCH * 512, 256, 0, stream>>>(x, xhp, xlp, xtp);
        energy_kernel     <<<BATCH * 36, 256, 0, stream>>>(xhp, xlp, e0);
        softmax_kernel    <<<BATCH * CCH, 256, 0, stream>>>(e0);
        out_kernel        <<<BATCH * 128, 256, 0, stream>>>(x, (const short*)e0, xtp, gamma, out);
    } else {
        // fallback (R7): xh | xl(->xt) | e0
        short* xhp = (short*)d_ws;
        short* xlp = (short*)((char*)d_ws + bfsz);
        float* e0  = (float*)((char*)d_ws + 2 * bfsz);
        split_kernel     <<<2048, 256, 0, stream>>>(x, xhp, xlp);
        energy_kernel    <<<BATCH * 36, 256, 0, stream>>>(xhp, xlp, e0);
        transpose_kernel <<<BATCH * 512, 256, 0, stream>>>(xhp, xlp);   // xl -> xt
        softmax_kernel   <<<BATCH * CCH, 256, 0, stream>>>(e0);
        out_kernel       <<<BATCH * 128, 256, 0, stream>>>(x, (const short*)e0, xlp, gamma, out);
    }
}

// Round 10
// 259.098 us; speedup vs baseline: 1.0163x; 1.0162x over previous
//
#include <hip/hip_runtime.h>

// CAM module: fused split+transpose (x -> xh, xl, xt); energy = q qT (bf16x3,
// symmetric tiles, 3-buffer counted-vmcnt pipeline); softmin -> bf16 attn;
// out = gamma*(attn q) + x (128x128, same pipeline template).
// B=16, C=512, N=64*64=4096

#define BATCH 16
#define CCH   512
#define NSP   4096

typedef __attribute__((ext_vector_type(8))) short bfx8;
typedef __attribute__((ext_vector_type(4))) short bfx4;
typedef __attribute__((ext_vector_type(4))) float fx4;
typedef __attribute__((ext_vector_type(2))) float fx2;

#define WAITV(N) asm volatile("s_waitcnt vmcnt(" #N ")" ::: "memory")

__device__ __forceinline__ short f2bf(float v) {
    union { float f; unsigned u; } a; a.f = v;
    unsigned r = a.u + 0x7fffu + ((a.u >> 16) & 1u);   // RNE
    return (short)(r >> 16);
}
__device__ __forceinline__ float bf2f(short s) {
    union { unsigned u; float f; } a; a.u = ((unsigned)(unsigned short)s) << 16;
    return a.f;
}

// async global(16B/lane) -> LDS (wave-uniform base + lane*16)
__device__ __forceinline__ void gload16(const short* g, short* l) {
    __builtin_amdgcn_global_load_lds((const __attribute__((address_space(1))) void*)g,
                                     (__attribute__((address_space(3))) void*)l, 16, 0, 0);
}

// ---------------- Kernel 0a (fused path): x -> xh, xl, and xt[b][n][c] ----------------
__global__ __launch_bounds__(256) void fused_split_kernel(const float* __restrict__ x,
                                                          short* __restrict__ xh,
                                                          short* __restrict__ xl,
                                                          short* __restrict__ xt) {
    int blk = blockIdx.x;              // 16*8*64 = 8192
    int b  = blk >> 9;
    int t  = blk & 511;
    int ct = t >> 6;                   // c-tile 0..7
    int nt = t & 63;                   // n-tile 0..63
    int c0 = ct * 64, n0 = nt * 64;
    const float* xb  = x  + (size_t)b * CCH * NSP;
    short*       xhb = xh + (size_t)b * CCH * NSP;
    short*       xlb = xl + (size_t)b * CCH * NSP;
    short*       xtb = xt + (size_t)b * NSP * CCH;

    __shared__ short A[64][64];        // [c][n], chunk ch at slot ch^(c&7)
    __shared__ short Bn[64][64];       // [n][c], chunk dr at slot dr^((n>>1)&7)

    int tid = threadIdx.x;

    // phase 1: read x rows, write xh/xl (coalesced), stash h in A
#pragma unroll
    for (int s = 0; s < 2; ++s) {
        int idx = s * 256 + tid;
        int row = idx >> 3;            // c-row 0..63
        int ch  = idx & 7;             // n-chunk
        const float* p = xb + (size_t)(c0 + row) * NSP + n0 + ch * 8;
        fx4 a = *(const fx4*)p;
        fx4 q = *(const fx4*)(p + 4);
        bfx8 h, l;
#pragma unroll
        for (int e = 0; e < 4; ++e) {
            short ha = f2bf(a[e]); h[e]     = ha; l[e]     = f2bf(a[e] - bf2f(ha));
            short hb = f2bf(q[e]); h[e + 4] = hb; l[e + 4] = f2bf(q[e] - bf2f(hb));
        }
        size_t go = (size_t)(c0 + row) * NSP + n0 + ch * 8;
        *(bfx8*)(xhb + go) = h;
        *(bfx8*)(xlb + go) = l;
        *(bfx8*)(&A[row][(ch ^ (row & 7)) * 8]) = h;
    }
    __syncthreads();

    // phase 2a: u32 column gather (n-pair 2p,2p+1 across 8 c-rows)
    int p  = tid & 31;
    int dr = tid >> 5;                 // c-oct 0..7
    unsigned wv[8];
#pragma unroll
    for (int i = 0; i < 8; ++i) {
        int r = dr * 8 + i;
        int byte = r * 128 + ((((p >> 2) ^ (r & 7)) * 8 + (2 * p & 7)) * 2);
        wv[i] = *(const unsigned*)((const char*)&A[0][0] + byte);
    }
    bfx8 q0, q1;
#pragma unroll
    for (int i = 0; i < 8; ++i) { q0[i] = (short)(wv[i] & 0xffff); q1[i] = (short)(wv[i] >> 16); }

    // phase 2b: write n-major tile
    int slot2 = dr ^ (p & 7);
    *(bfx8*)(&Bn[2 * p][slot2 * 8])     = q0;
    *(bfx8*)(&Bn[2 * p + 1][slot2 * 8]) = q1;
    __syncthreads();

    // phase 2c: coalesced xt row writes (non-temporal: read much later, keep L2 for xh/xl)
#pragma unroll
    for (int it = 0; it < 2; ++it) {
        int n  = it * 32 + (tid >> 3);
        int ch = tid & 7;
        bfx8 v = *(const bfx8*)(&Bn[n][(ch ^ ((n >> 1) & 7)) * 8]);
        __builtin_nontemporal_store(v, (bfx8*)(xtb + (size_t)(n0 + n) * CCH + c0 + ch * 8));
    }
}

// ---------------- Kernel 0b (fallback): split x -> xh + xl ----------------
__global__ __launch_bounds__(256) void split_kernel(const float* __restrict__ x,
                                                    short* __restrict__ xh,
                                                    short* __restrict__ xl) {
    size_t stride = (size_t)gridDim.x * 256;
    size_t total8 = (size_t)BATCH * CCH * NSP / 8;
    for (size_t u = (size_t)blockIdx.x * 256 + threadIdx.x; u < total8; u += stride) {
        size_t i = u * 8;
        fx4 a = *(const fx4*)(x + i);
        fx4 b = *(const fx4*)(x + i + 4);
        bfx8 h, l;
#pragma unroll
        for (int e = 0; e < 4; ++e) {
            short ha = f2bf(a[e]); h[e]     = ha; l[e]     = f2bf(a[e] - bf2f(ha));
            short hb = f2bf(b[e]); h[e + 4] = hb; l[e + 4] = f2bf(b[e] - bf2f(hb));
        }
        *(bfx8*)(xh + i) = h;
        *(bfx8*)(xl + i) = l;
    }
}

// ---------------- Kernel 1: energy = q qT, bf16x3, symmetric tiles ----------------
// 64x64 tile, 4 waves (32x32), BK=32, 3-buffer LDS (48 KiB), counted vmcnt(4):
// two STAGEs (4 loads/wave each) always in flight; never drain to 0 mid-loop.
__global__ __launch_bounds__(256, 3) void energy_kernel(const short* __restrict__ xh,
                                                        const short* __restrict__ xl,
                                                        float* __restrict__ energy) {
    int orig = blockIdx.x;
    int wgid = (orig & 7) * 72 + (orig >> 3);   // 576 = 8 xcds x 72
    int b = wgid / 36;
    int t = wgid % 36;
    int ti = 0, rem = t;
    while (rem >= 8 - ti) { rem -= 8 - ti; ++ti; }
    int tj = ti + rem;
    int c0 = ti * 64, d0 = tj * 64;
    bool diag = (ti == tj);
    const short* qh = xh + (size_t)b * CCH * NSP;
    const short* ql = xl + (size_t)b * CCH * NSP;

    __shared__ short S[3][4][64][32];   // [buf][Ah,Al,Bh,Bl][row][k] = 48 KiB

    int tid  = threadIdx.x;
    int lane = tid & 63;
    int w    = tid >> 6;
    int wr   = (w >> 1) * 32;
    int wc   = (w & 1) * 32;

    int rb   = w * 16;
    int srow = lane >> 2;                       // 0..15
    int gch  = (lane & 3) ^ ((lane >> 3) & 3);  // pre-swizzled source chunk

    // uniform 4 loads/wave per STAGE (diag stages B too -> uniform vmcnt math)
    auto STAGE = [&](int buf, int kt) {
        size_t koff = (size_t)kt * 32 + gch * 8;
        gload16(qh + (size_t)(c0 + rb + srow) * NSP + koff, &S[buf][0][rb][0]);
        gload16(ql + (size_t)(c0 + rb + srow) * NSP + koff, &S[buf][1][rb][0]);
        gload16(qh + (size_t)(d0 + rb + srow) * NSP + koff, &S[buf][2][rb][0]);
        gload16(ql + (size_t)(d0 + rb + srow) * NSP + koff, &S[buf][3][rb][0]);
    };

    fx4 acc[2][2];
#pragma unroll
    for (int i = 0; i < 2; i++)
#pragma unroll
        for (int j = 0; j < 2; j++) acc[i][j] = (fx4)(0.0f);

    STAGE(0, 0);
    STAGE(1, 1);

    const char* Sb = (const char*)&S[0][0][0][0];
    int h = lane >> 4;
    int cur = 0;
    const int NT = NSP / 32;            // 128
    for (int kt = 0; kt < NT; ++kt) {
        // oldest STAGE landed (own 4 loads); newest (4) may fly across the barrier
        if (kt < NT - 1) WAITV(4); else WAITV(0);
        __builtin_amdgcn_s_barrier();
        __builtin_amdgcn_sched_barrier(0);   // pin ds_reads after barrier

        bfx8 ah_[2], al_[2], bh_[2], bl_[2];
        const char* Sc = Sb + cur * (4 * 4096);
#pragma unroll
        for (int mi = 0; mi < 2; ++mi) {
            int r  = wr + mi * 16 + (lane & 15);
            int bo = r * 64 + ((h ^ ((r >> 1) & 3)) << 4);
            ah_[mi] = *(const bfx8*)(Sc + 0 * 4096 + bo);
            al_[mi] = *(const bfx8*)(Sc + 1 * 4096 + bo);
        }
#pragma unroll
        for (int ni = 0; ni < 2; ++ni) {
            int r  = wc + ni * 16 + (lane & 15);
            int bo = r * 64 + ((h ^ ((r >> 1) & 3)) << 4);
            bh_[ni] = *(const bfx8*)(Sc + 2 * 4096 + bo);
            bl_[ni] = *(const bfx8*)(Sc + 3 * 4096 + bo);
        }
        // stage tile kt+2 into the buffer last read at iter kt-1 (all readers done)
        if (kt + 2 < NT) {
            int nb = cur + 2; if (nb >= 3) nb -= 3;
            STAGE(nb, kt + 2);
        }
        __builtin_amdgcn_s_setprio(1);
#pragma unroll
        for (int mi = 0; mi < 2; ++mi)
#pragma unroll
            for (int ni = 0; ni < 2; ++ni) {
                acc[mi][ni] = __builtin_amdgcn_mfma_f32_16x16x32_bf16(ah_[mi], bh_[ni], acc[mi][ni], 0, 0, 0);
                acc[mi][ni] = __builtin_amdgcn_mfma_f32_16x16x32_bf16(ah_[mi], bl_[ni], acc[mi][ni], 0, 0, 0);
                acc[mi][ni] = __builtin_amdgcn_mfma_f32_16x16x32_bf16(al_[mi], bh_[ni], acc[mi][ni], 0, 0, 0);
            }
        __builtin_amdgcn_s_setprio(0);
        cur = (cur == 2) ? 0 : cur + 1;
    }

    int colw = lane & 15;
    int rowg = (lane >> 4) * 4;
#pragma unroll
    for (int mi = 0; mi < 2; ++mi)
#pragma unroll
        for (int ni = 0; ni < 2; ++ni) {
            int cb = c0 + wr + mi * 16 + rowg;
            int d  = d0 + wc + ni * 16 + colw;
#pragma unroll
            for (int r = 0; r < 4; ++r) {
                int c = cb + r;
                float v = acc[mi][ni][r];
                energy[((size_t)b * CCH + c) * CCH + d] = v;
                if (!diag)
                    energy[((size_t)b * CCH + d) * CCH + c] = v;
            }
        }
}

// ---------------- Kernel 1.5 (fallback): transpose xh[b][c][n] -> xt[b][n][c] ----------------
__global__ __launch_bounds__(256) void transpose_kernel(const short* __restrict__ xh,
                                                        short* __restrict__ xt) {
    int blk = blockIdx.x;              // 8192
    int b  = blk >> 9;
    int t  = blk & 511;
    int ct = t >> 6;
    int nt = t & 63;
    int c0 = ct * 64, n0 = nt * 64;
    const short* src = xh + (size_t)b * CCH * NSP;
    short*       dst = xt + (size_t)b * NSP * CCH;

    __shared__ short Lt[64][64];

    int tid = threadIdx.x;
    int p  = tid & 31;
    int dr = tid >> 5;

    unsigned wv[8];
    const short* sp = src + (size_t)(c0 + dr * 8) * NSP + n0 + 2 * p;
#pragma unroll
    for (int i = 0; i < 8; ++i) wv[i] = *(const unsigned*)(sp + (size_t)i * NSP);
    bfx8 q0, q1;
#pragma unroll
    for (int i = 0; i < 8; ++i) { q0[i] = (short)(wv[i] & 0xffff); q1[i] = (short)(wv[i] >> 16); }
    int slot = dr ^ (p & 7);
    *(bfx8*)(&Lt[0][0] + (2 * p) * 64 + slot * 8)     = q0;
    *(bfx8*)(&Lt[0][0] + (2 * p + 1) * 64 + slot * 8) = q1;
    __syncthreads();

#pragma unroll
    for (int it = 0; it < 2; ++it) {
        int n  = it * 32 + (tid >> 3);
        int ch = tid & 7;
        bfx8 v = *(const bfx8*)(&Lt[0][0] + n * 64 + (ch ^ ((n >> 1) & 7)) * 8);
        *(bfx8*)(dst + (size_t)(n0 + n) * CCH + c0 + ch * 8) = v;
    }
}

// ---------------- Kernel 2: softmin over rows; writes bf16 attn in-place ----------------
__global__ __launch_bounds__(256) void softmax_kernel(float* __restrict__ energy) {
    size_t row = blockIdx.x;
    float* e = energy + row * CCH;
    int tid = threadIdx.x;
    fx2 v = *(const fx2*)(e + 2 * tid);

    float m = fminf(v[0], v[1]);
#pragma unroll
    for (int off = 32; off; off >>= 1) m = fminf(m, __shfl_xor(m, off));
    __shared__ float redm[4];
    __shared__ float reds[4];
    if ((tid & 63) == 0) redm[tid >> 6] = m;
    __syncthreads();
    m = fminf(fminf(redm[0], redm[1]), fminf(redm[2], redm[3]));

    float w0 = __expf(m - v[0]);
    float w1 = __expf(m - v[1]);
    float s = w0 + w1;
#pragma unroll
    for (int off = 32; off; off >>= 1) s += __shfl_xor(s, off);
    if ((tid & 63) == 0) reds[tid >> 6] = s;
    __syncthreads();
    s = (reds[0] + reds[1]) + (reds[2] + reds[3]);
    float inv = 1.0f / s;
    unsigned uw = ((unsigned)(unsigned short)f2bf(w0 * inv)) |
                  (((unsigned)(unsigned short)f2bf(w1 * inv)) << 16);
    ((unsigned*)e)[tid] = uw;   // safe: all reads completed before barriers
}

// ---------------- Kernel 3: out = gamma * (attn @ q) + x ----------------
// 128x128 tile, BK=32, 4 waves each owning 64x64. Same 3-buffer counted-vmcnt
// pipeline as energy_kernel (4 gload_lds/wave per STAGE).
__global__ __launch_bounds__(256, 3) void out_kernel(const float* __restrict__ x,
                                                     const short* __restrict__ attnb, // 1024-short rows
                                                     const short* __restrict__ xt,    // [n][c] bf16
                                                     const float* __restrict__ gamma,
                                                     float* __restrict__ out) {
    int orig = blockIdx.x;
    int blk  = (orig & 7) * 256 + (orig >> 3);   // 2048 = 8 x 256
    int b   = blk >> 7;
    int t   = blk & 127;
    int c0  = (t >> 5) * 128;
    int n0  = (t & 31) * 128;
    const float* xb = x + (size_t)b * CCH * NSP;
    const short* ab = attnb + (size_t)b * CCH * 1024;
    const short* qt = xt + (size_t)b * NSP * CCH;

    __shared__ short SA[3][128][32];    // 24 KiB
    __shared__ short SB[3][128][32];    // 24 KiB

    int tid  = threadIdx.x;
    int lane = tid & 63;
    int w    = tid >> 6;
    int wr   = (w >> 1) * 64;
    int wc   = (w & 1) * 64;

    int srow = lane >> 2;
    int gch  = (lane & 3) ^ ((lane >> 3) & 3);

    auto STAGE = [&](int buf, int kt) {
#pragma unroll
        for (int hf = 0; hf < 2; ++hf) {
            int rg = hf * 64 + w * 16;
            gload16(ab + (size_t)(c0 + rg + srow) * 1024 + kt * 32 + gch * 8, &SA[buf][rg][0]);
            gload16(qt + (size_t)(n0 + rg + srow) * 512  + kt * 32 + gch * 8, &SB[buf][rg][0]);
        }
    };

    fx4 acc[4][4];
#pragma unroll
    for (int i = 0; i < 4; i++)
#pragma unroll
        for (int j = 0; j < 4; j++) acc[i][j] = (fx4)(0.0f);

    STAGE(0, 0);
    STAGE(1, 1);

    int h = lane >> 4;
    int cur = 0;
    const int NT = CCH / 32;            // 16
    for (int kt = 0; kt < NT; ++kt) {
        if (kt < NT - 1) WAITV(4); else WAITV(0);
        __builtin_amdgcn_s_barrier();
        __builtin_amdgcn_sched_barrier(0);

        bfx8 af[4], bf[4];
#pragma unroll
        for (int mi = 0; mi < 4; ++mi) {
            int r  = wr + mi * 16 + (lane & 15);
            af[mi] = *(const bfx8*)((const char*)&SA[cur][0][0] + r * 64 + ((h ^ ((r >> 1) & 3)) << 4));
        }
#pragma unroll
        for (int ni = 0; ni < 4; ++ni) {
            int r  = wc + ni * 16 + (lane & 15);
            bf[ni] = *(const bfx8*)((const char*)&SB[cur][0][0] + r * 64 + ((h ^ ((r >> 1) & 3)) << 4));
        }
        if (kt + 2 < NT) {
            int nb = cur + 2; if (nb >= 3) nb -= 3;
            STAGE(nb, kt + 2);
        }
        __builtin_amdgcn_s_setprio(1);
#pragma unroll
        for (int mi = 0; mi < 4; ++mi)
#pragma unroll
            for (int ni = 0; ni < 4; ++ni)
                acc[mi][ni] = __builtin_amdgcn_mfma_f32_16x16x32_bf16(af[mi], bf[ni], acc[mi][ni], 0, 0, 0);
        __builtin_amdgcn_s_setprio(0);
        cur = (cur == 2) ? 0 : cur + 1;
    }

    float g = gamma[0];
    int colw = lane & 15;
    int rowg = (lane >> 4) * 4;
#pragma unroll
    for (int mi = 0; mi < 4; ++mi)
#pragma unroll
        for (int ni = 0; ni < 4; ++ni) {
            int n = n0 + wc + ni * 16 + colw;
#pragma unroll
            for (int r = 0; r < 4; ++r) {
                int c = c0 + wr + mi * 16 + rowg + r;
                size_t off = ((size_t)b * CCH + c) * NSP + n;
                out[off] = g * acc[mi][ni][r] + xb[(size_t)c * NSP + n];
            }
        }
}

extern "C" void kernel_launch(void* const* d_in, const int* in_sizes, int n_in,
                              void* d_out, int out_size, void* d_ws, size_t ws_size,
                              hipStream_t stream) {
    (void)in_sizes; (void)n_in; (void)out_size;
    const float* x     = (const float*)d_in[0];
    const float* gamma = (const float*)d_in[1];
    float*       out   = (float*)d_out;

    size_t nel  = (size_t)BATCH * CCH * NSP;
    size_t bfsz = nel * sizeof(short);                   // ~67 MB
    size_t esz  = (size_t)BATCH * CCH * CCH * 4;         // ~17 MB

    if (ws_size >= 3 * bfsz + esz) {
        // fused path: xh | xl | xt | e0
        short* xhp = (short*)d_ws;
        short* xlp = (short*)((char*)d_ws + bfsz);
        short* xtp = (short*)((char*)d_ws + 2 * bfsz);
        float* e0  = (float*)((char*)d_ws + 3 * bfsz);
        fused_split_kernel<<<BATCH * 512, 256, 0, stream>>>(x, xhp, xlp, xtp);
        energy_kernel     <<<BATCH * 36, 256, 0, stream>>>(xhp, xlp, e0);
        softmax_kernel    <<<BATCH * CCH, 256, 0, stream>>>(e0);
        out_kernel        <<<BATCH * 128, 256, 0, stream>>>(x, (const short*)e0, xtp, gamma, out);
    } else {
        // fallback: xh | xl(->xt) | e0
        short* xhp = (short*)d_ws;
        short* xlp = (short*)((char*)d_ws + bfsz);
        float* e0  = (float*)((char*)d_ws + 2 * bfsz);
        split_kernel     <<<2048, 256, 0, stream>>>(x, xhp, xlp);
        energy_kernel    <<<BATCH * 36, 256, 0, stream>>>(xhp, xlp, e0);
        transpose_kernel <<<BATCH * 512, 256, 0, stream>>>(xhp, xlp);   // xl -> xt
        softmax_kernel   <<<BATCH * CCH, 256, 0, stream>>>(e0);
        out_kernel       <<<BATCH * 128, 256, 0, stream>>>(x, (const short*)e0, xlp, gamma, out);
    }
}